// Round 4
// baseline (117.404 us; speedup 1.0000x reference)
//
#include <hip/hip_runtime.h>

// GraphPairClassifier v17: v16 + cross-layer B prefetch + wide prep.
//   (a) bbuf hoisted to caller-owned registers: each layer's 3 warmup B-slot
//       loads (global, barrier-independent) are issued BEFORE the preceding
//       __syncthreads (L2's at kernel cycle 0, under Phase -1/0/1) -> the
//       per-layer L2-latency warmup stall (~200-400 cyc x 6 layers) is hidden.
//       Zero extra registers: preload reuses the just-died bbuf slots.
//   (b) prep re-mapped: 35328 threads x 8 float2 strided loads + one 32B
//       write (thread owns lanes 2t,2t+1 of a fragment) — half the
//       instructions, value-identical output.
//   Everything else = v16: 250 blocks x 50 pairs x 1024 thr (16 waves,
//   4/SIMD), ping-pong LDS, m-split L2/L3/H2/H3, transposed-MFMA D^T
//   epilogue with packed half4/dwordx4 stores, distance-3 B prefetch.
// Dtypes: device inputs FP32 (bf16-quantized values => fp16 weights exact);
//   output FP32. absmax 3.9e-3 stable R6-R16.

typedef _Float16 half8  __attribute__((ext_vector_type(8)));
typedef _Float16 half4  __attribute__((ext_vector_type(4)));
typedef _Float16 half16 __attribute__((ext_vector_type(16)));
typedef float floatx4 __attribute__((ext_vector_type(4)));

// -------- weight prep: fp32 [K,N] row-major -> fp16 16x16x32-fragment order -
// Storage slot f (half8): lane=f&63, rem=f>>6, nt=rem%(N/16), kb=rem/(N/16);
//   n = nt*16+(lane&15), k = kb*32+(lane>>4)*8+j.
// v17 unit u = slots {2u, 2u+1} (lanes l0=2t, l0+1 of rem=u>>5, t=u&31):
//   8 x float2 strided reads (n0 even), one 32B contiguous write.
struct PrepArgsV17 { const float* in[6]; };

__global__ __launch_bounds__(256) void v17_prep(PrepArgsV17 p, _Float16* Bf) {
  const int units[6] = {4096, 4096, 16384, 8192, 2048, 512};  // sz/16
  const int lgN[6]   = {8, 8, 9, 8, 7, 6};
  const int off[6]   = {0, 65536, 131072, 393216, 524288, 557056};
  int u = blockIdx.x * 256 + threadIdx.x;           // 138 blocks x 256 = 35328
  for (int i = 0; i < 6; ++i) {
    if (u < units[i]) {
      int N = 1 << lgN[i];
      int t = u & 31, rem = u >> 5;
      int nt = rem & ((N >> 4) - 1);
      int kb = rem >> (lgN[i] - 4);
      int lr0 = (2 * t) & 15;                       // even, lanes l0 & l0+1 same quad
      int quad = t >> 3;
      int n0 = nt * 16 + lr0;
      int k0 = kb * 32 + quad * 8;
      const float* src = p.in[i] + (size_t)k0 * N + n0;
      half16 w;
#pragma unroll
      for (int j = 0; j < 8; ++j) {
        float2 f2 = *(const float2*)(src + (size_t)j * N);   // 8B aligned (n0 even)
        w[j]     = (_Float16)f2.x;                  // slot 2u   (lane l0,   n0)
        w[8 + j] = (_Float16)f2.y;                  // slot 2u+1 (lane l0+1, n0+1)
      }
      *(half16*)(Bf + off[i] + (size_t)u * 16) = w; // 32B store, exact (bf16-valued)
      return;
    }
    u -= units[i];
  }
}

// -------- cross-layer B warmup: load k-steps 0..2 into caller-owned bbuf ----
template<int NT, int TNT>
__device__ __forceinline__ void preload(half8 (&bbuf)[4][2], const _Float16* bp) {
#pragma unroll
  for (int s = 0; s < 3; ++s)
#pragma unroll
    for (int nt = 0; nt < NT; ++nt)
      bbuf[s][nt] = *(const half8*)(bp + (size_t)s * (TNT * 512) + nt * 512);
}

// -------- generic ping-pong layer, distance-3 B prefetch, D^T epilogue -----
// MT m-tiles (16 rows from m0), NT n-tiles at n-slot nw, TNT = N/16 total
// n-tiles, KB k-steps of 32. ENC_IN: srcA stride 264 halves; else 520.
// OUT_MODE 0: relu->encode(dst); 1: relu->head concat(dst); 2: relu->head(dst);
//          3: sigmoid->global fp32 (rows r<50 only).
// bbuf slots 0..2 arrive PRELOADED by the caller (issued pre-barrier).
// mfma(a_op=W frag, b_op=Act frag) => D^T: r = m0+mt*16+(lane&15),
//   c = n0+nt*16+quad*4+reg (4 consecutive cols per lane -> packed writes).
// NO trailing barrier here — caller syncs (calls may be wave-divergent).
template<int MT, int NT, int TNT, int KB, bool ENC_IN, int OUT_MODE>
__device__ __forceinline__ void layer(
    const _Float16* __restrict__ Bf, const float* __restrict__ bias,
    const _Float16* __restrict__ srcA, _Float16* dstA, float* __restrict__ outg,
    half8 (&bbuf)[4][2], int pair0, int nw, int m0, int lane) {
  const int quad = lane >> 4, lr = lane & 15;
  const int n0 = nw * (NT * 16);
  const int STRIDE = ENC_IN ? 264 : 520;
  const _Float16* bp = Bf + ((size_t)(nw * NT) * 64 + lane) * 8;

  floatx4 acc[MT][NT];
#pragma unroll
  for (int mt = 0; mt < MT; ++mt)
#pragma unroll
    for (int nt = 0; nt < NT; ++nt)
      acc[mt][nt] = (floatx4){0.f, 0.f, 0.f, 0.f};

#pragma unroll
  for (int kb = 0; kb < KB; ++kb) {
    const int cur = kb & 3;
    half8 av[MT];
#pragma unroll
    for (int mt = 0; mt < MT; ++mt)
      av[mt] = *(const half8*)(srcA + (m0 + mt * 16 + lr) * STRIDE + kb * 32 + quad * 8);
#pragma unroll
    for (int nt = 0; nt < NT; ++nt)
#pragma unroll
      for (int mt = 0; mt < MT; ++mt)
        acc[mt][nt] = __builtin_amdgcn_mfma_f32_16x16x32_f16(bbuf[cur][nt], av[mt], acc[mt][nt], 0, 0, 0);
    if (kb + 3 < KB) {
      const int nxt = (kb + 3) & 3;
#pragma unroll
      for (int nt = 0; nt < NT; ++nt)
        bbuf[nxt][nt] = *(const half8*)(bp + (size_t)(kb + 3) * (TNT * 512) + nt * 512);
    }
  }

  // epilogue straight after own MFMAs: dst buffer != src buffer (no WAR)
#pragma unroll
  for (int nt = 0; nt < NT; ++nt) {
    const int c0 = n0 + nt * 16 + quad * 4;
    const floatx4 bv = *(const floatx4*)(bias + c0);
#pragma unroll
    for (int mt = 0; mt < MT; ++mt) {
      const int r = m0 + mt * 16 + lr;
      floatx4 v = acc[mt][nt] + bv;
      if (OUT_MODE <= 2) {
        half4 h;
#pragma unroll
        for (int reg = 0; reg < 4; ++reg) h[reg] = (_Float16)fmaxf(v[reg], 0.f);
        int a;
        if (OUT_MODE == 0)      a = r * 264 + c0;                         // encode
        else if (OUT_MODE == 1) a = (r >> 1) * 520 + (r & 1) * 256 + c0;  // concat
        else                    a = r * 520 + c0;                         // head
        *(half4*)(dstA + a) = h;                                          // 8B write
      } else {
        if (r < 50) {
          floatx4 o;
#pragma unroll
          for (int reg = 0; reg < 4; ++reg) o[reg] = 1.0f / (1.0f + expf(-v[reg]));
          *(floatx4*)(outg + (size_t)(pair0 + r) * 64 + c0) = o;          // 16B store
        }
      }
    }
  }
}

// -------- megakernel: 50 pairs (100 side rows, pad 112) per 1024-thr block --
__global__ __launch_bounds__(1024) void v17_mega(
    const float* __restrict__ x1, const float* __restrict__ x2,
    const float* __restrict__ W1, const float* __restrict__ b1,
    const _Float16* __restrict__ Bf,
    const float* __restrict__ b2, const float* __restrict__ b3,
    const float* __restrict__ bl1, const float* __restrict__ bl2,
    const float* __restrict__ bl3, const float* __restrict__ bl4,
    float* __restrict__ outg) {
  // ping-pong buffers: encode [112][264]=29568 halves; head [64][520]=33280
  __shared__ _Float16 sB0[33280];
  __shared__ _Float16 sB1[33280];
  __shared__ float sM[112][3];

  int tid = threadIdx.x;
  int wave = tid >> 6, lane = tid & 63;
  int pair0 = blockIdx.x * 50;
  int nwA = (wave < 8) ? wave : wave - 8;   // n-slot for the m-split layers

  // issue L2's B warmup at cycle 0 — hidden under Phase -1/0/1
  half8 bbuf[4][2];
  preload<2, 16>(bbuf, Bf + ((size_t)(nwA * 2) * 64 + lane) * 8);

  // Phase -1: guarantee sB0 is fully finite after L1. L1 writes encode halves
  // [0,29568); H1 later reads head rows 56..63 = halves [29120,33280). Zero
  // the never-written tail [29568,33280) plus overlap (cheap, one pass).
  for (int i = tid; i < 2080; i += 1024) ((float*)sB0)[14560 + i] = 0.f;

  // Phase 0: per-side-row mean of the 4 node coords (100 real rows, 12 pad)
  if (tid < 112) {
    int r = tid;
    float a0 = 0.f, a1 = 0.f, a2 = 0.f;
    if (r < 100) {
      int g = pair0 + (r >> 1);                    // always < 12500
      const float* q = ((r & 1) ? x2 : x1) + (size_t)g * 12;
      a0 = 0.25f * (q[0] + q[3] + q[6] + q[9]);
      a1 = 0.25f * (q[1] + q[4] + q[7] + q[10]);
      a2 = 0.25f * (q[2] + q[5] + q[8] + q[11]);
    }
    sM[r][0] = a0; sM[r][1] = a1; sM[r][2] = a2;
  }
  __syncthreads();

  // Phase 1: L1 (3 -> 256), fp32 VALU, packed half4 writes into sB0.
  {
    int c4 = (tid & 63) * 4;          // 0..252
    int rb = tid >> 6;                // 0..15
    floatx4 w0 = *(const floatx4*)(W1 + c4);
    floatx4 w1 = *(const floatx4*)(W1 + 256 + c4);
    floatx4 w2 = *(const floatx4*)(W1 + 512 + c4);
    floatx4 bb = *(const floatx4*)(b1 + c4);
    for (int r = rb; r < 112; r += 16) {
      float s0 = sM[r][0], s1 = sM[r][1], s2 = sM[r][2];
      half4 h;
#pragma unroll
      for (int j = 0; j < 4; ++j) {
        float v = fmaxf(s0 * w0[j] + s1 * w1[j] + s2 * w2[j] + bb[j], 0.f);
        h[j] = (_Float16)v;
      }
      *(half4*)(sB0 + r * 264 + c4) = h;
    }
  }
  __syncthreads();

  // L2: [112x256]@[256x256] relu, sB0->sB1   (Wn=8 x Wm=2: rows 0..63 / 64..111)
  if (wave < 8) layer<4, 2, 16,  8, true,  0>(Bf + 0,      b2,  sB0, sB1, nullptr, bbuf, pair0, nwA, 0,  lane);
  else          layer<3, 2, 16,  8, true,  0>(Bf + 0,      b2,  sB0, sB1, nullptr, bbuf, pair0, nwA, 64, lane);
  preload<2, 16>(bbuf, Bf + 65536 + ((size_t)(nwA * 2) * 64 + lane) * 8);
  __syncthreads();
  // L3: [112x256]@[256x256] relu, sB1->sB0 (concat head layout)
  if (wave < 8) layer<4, 2, 16,  8, true,  1>(Bf + 65536,  b3,  sB1, sB0, nullptr, bbuf, pair0, nwA, 0,  lane);
  else          layer<3, 2, 16,  8, true,  1>(Bf + 65536,  b3,  sB1, sB0, nullptr, bbuf, pair0, nwA, 64, lane);
  preload<2, 32>(bbuf, Bf + 131072 + ((size_t)(wave * 2) * 64 + lane) * 8);
  __syncthreads();
  // H1: [64x512]@[512x512] relu, sB0->sB1    (Wn=16 x NT=2; B-heavy, no m-split)
  layer<4, 2, 32, 16, false, 2>(Bf + 131072, bl1, sB0, sB1, nullptr, bbuf, pair0, wave, 0, lane);
  preload<2, 16>(bbuf, Bf + 393216 + ((size_t)(nwA * 2) * 64 + lane) * 8);
  __syncthreads();
  // H2: [64x512]@[512x256] relu, sB1->sB0    (Wn=8 x Wm=2: rows 0..31 / 32..63)
  if (wave < 8) layer<2, 2, 16, 16, false, 2>(Bf + 393216, bl2, sB1, sB0, nullptr, bbuf, pair0, nwA, 0,  lane);
  else          layer<2, 2, 16, 16, false, 2>(Bf + 393216, bl2, sB1, sB0, nullptr, bbuf, pair0, nwA, 32, lane);
  preload<1, 8>(bbuf, Bf + 524288 + ((size_t)((wave & 7)) * 64 + lane) * 8);
  __syncthreads();
  // H3: [64x256]@[256x128] relu, sB0->sB1    (Wn=8 x Wm=2)
  layer<2, 1,  8,  8, false, 2>(Bf + 524288, bl3, sB0, sB1, nullptr, bbuf, pair0,
                                wave & 7, (wave >> 3) * 32, lane);
  preload<1, 4>(bbuf, Bf + 557056 + ((size_t)((wave & 3)) * 64 + lane) * 8);
  __syncthreads();
  // H4: [64x128]@[128x64] sigmoid -> global  (Wn=4 x Wm=4)
  layer<1, 1,  4,  4, false, 3>(Bf + 557056, bl4, sB1, nullptr, outg, bbuf, pair0,
                                wave & 3, (wave >> 2) * 16, lane);
}

extern "C" void kernel_launch(void* const* d_in, const int* in_sizes, int n_in,
                              void* d_out, int out_size, void* d_ws, size_t ws_size,
                              hipStream_t stream) {
  const float* x1  = (const float*)d_in[0];
  const float* x2  = (const float*)d_in[3];
  const float* W1  = (const float*)d_in[6];
  const float* b1  = (const float*)d_in[7];
  const float* W2  = (const float*)d_in[8];
  const float* b2  = (const float*)d_in[9];
  const float* W3  = (const float*)d_in[10];
  const float* b3  = (const float*)d_in[11];
  const float* Wl1 = (const float*)d_in[12];
  const float* bl1 = (const float*)d_in[13];
  const float* Wl2 = (const float*)d_in[14];
  const float* bl2 = (const float*)d_in[15];
  const float* Wl3 = (const float*)d_in[16];
  const float* bl3 = (const float*)d_in[17];
  const float* Wl4 = (const float*)d_in[18];
  const float* bl4 = (const float*)d_in[19];

  _Float16* Bf = (_Float16*)d_ws;   // 565248 halves = 1.13 MB

  PrepArgsV17 pa;
  pa.in[0] = W2;  pa.in[1] = W3;  pa.in[2] = Wl1;
  pa.in[3] = Wl2; pa.in[4] = Wl3; pa.in[5] = Wl4;

  v17_prep<<<dim3(138), dim3(256), 0, stream>>>(pa, Bf);
  v17_mega<<<dim3(250), dim3(1024), 0, stream>>>(x1, x2, W1, b1, Bf,
                                                 b2, b3, bl1, bl2, bl3, bl4,
                                                 (float*)d_out);
}

// Round 5
// 116.669 us; speedup vs baseline: 1.0063x; 1.0063x over previous
//
#include <hip/hip_runtime.h>

// GraphPairClassifier v18: v16 core + v17 prep + bias-hoist + setprio.
//   R17 post-mortem: cross-layer B preload REGRESSED (+1.7us) — compiler
//   emits s_waitcnt vmcnt(0) before every s_barrier, so pre-barrier loads
//   are DRAINED AT the barrier (adding L2 latency to the critical path),
//   not hidden. Reverted to layer-local bbuf (v16). Lesson kept: no fresh
//   global loads between MFMA-end and a barrier -> bias loads hoisted to
//   layer entry (latency hides under K-loop; zero vmem pending at barrier).
//   Added T5 s_setprio(1/0) around each kb MFMA cluster (wave role
//   diversity exists: 4-vs-3 m-split imbalance + staggered epilogues).
//   Geometry unchanged: 250 blocks x 50 pairs x 1024 thr (16 waves, 4/SIMD),
//   ping-pong LDS, m-split L2/L3/H2/H3, transposed-MFMA D^T epilogue with
//   packed half4/dwordx4 stores, distance-3 B prefetch, wide float2 prep.
// Dtypes: device inputs FP32 (bf16-quantized values => fp16 weights exact);
//   output FP32. absmax 3.9e-3 stable R6-R17.

typedef _Float16 half8  __attribute__((ext_vector_type(8)));
typedef _Float16 half4  __attribute__((ext_vector_type(4)));
typedef _Float16 half16 __attribute__((ext_vector_type(16)));
typedef float floatx4 __attribute__((ext_vector_type(4)));

// -------- weight prep: fp32 [K,N] row-major -> fp16 16x16x32-fragment order -
// Storage slot f (half8): lane=f&63, rem=f>>6, nt=rem%(N/16), kb=rem/(N/16);
//   n = nt*16+(lane&15), k = kb*32+(lane>>4)*8+j.
// Unit u = slots {2u, 2u+1} (lanes l0=2t, l0+1 of rem=u>>5, t=u&31):
//   8 x float2 strided reads (n0 even), one 32B contiguous write.
struct PrepArgsV18 { const float* in[6]; };

__global__ __launch_bounds__(256) void v18_prep(PrepArgsV18 p, _Float16* Bf) {
  const int units[6] = {4096, 4096, 16384, 8192, 2048, 512};  // sz/16
  const int lgN[6]   = {8, 8, 9, 8, 7, 6};
  const int off[6]   = {0, 65536, 131072, 393216, 524288, 557056};
  int u = blockIdx.x * 256 + threadIdx.x;           // 138 blocks x 256 = 35328
  for (int i = 0; i < 6; ++i) {
    if (u < units[i]) {
      int N = 1 << lgN[i];
      int t = u & 31, rem = u >> 5;
      int nt = rem & ((N >> 4) - 1);
      int kb = rem >> (lgN[i] - 4);
      int lr0 = (2 * t) & 15;                       // even, lanes l0 & l0+1 same quad
      int quad = t >> 3;
      int n0 = nt * 16 + lr0;
      int k0 = kb * 32 + quad * 8;
      const float* src = p.in[i] + (size_t)k0 * N + n0;
      half16 w;
#pragma unroll
      for (int j = 0; j < 8; ++j) {
        float2 f2 = *(const float2*)(src + (size_t)j * N);   // 8B aligned (n0 even)
        w[j]     = (_Float16)f2.x;                  // slot 2u   (lane l0,   n0)
        w[8 + j] = (_Float16)f2.y;                  // slot 2u+1 (lane l0+1, n0+1)
      }
      *(half16*)(Bf + off[i] + (size_t)u * 16) = w; // 32B store, exact (bf16-valued)
      return;
    }
    u -= units[i];
  }
}

// -------- generic ping-pong layer, distance-3 B prefetch, D^T epilogue -----
// MT m-tiles (16 rows from m0), NT n-tiles at n-slot nw, TNT = N/16 total
// n-tiles, KB k-steps of 32. ENC_IN: srcA stride 264 halves; else 520.
// OUT_MODE 0: relu->encode(dst); 1: relu->head concat(dst); 2: relu->head(dst);
//          3: sigmoid->global fp32 (rows r<50 only).
// mfma(a_op=W frag, b_op=Act frag) => D^T: r = m0+mt*16+(lane&15),
//   c = n0+nt*16+quad*4+reg (4 consecutive cols per lane -> packed writes).
// Bias loaded at ENTRY (latency hides under K-loop; no vmem pending at the
// caller's barrier). NO trailing barrier here — caller syncs.
template<int MT, int NT, int TNT, int KB, bool ENC_IN, int OUT_MODE>
__device__ __forceinline__ void layer(
    const _Float16* __restrict__ Bf, const float* __restrict__ bias,
    const _Float16* __restrict__ srcA, _Float16* dstA, float* __restrict__ outg,
    int pair0, int nw, int m0, int lane) {
  const int quad = lane >> 4, lr = lane & 15;
  const int n0 = nw * (NT * 16);
  const int STRIDE = ENC_IN ? 264 : 520;
  const _Float16* bp = Bf + ((size_t)(nw * NT) * 64 + lane) * 8;

  // bias hoist: issue global loads now, consume after the K-loop
  floatx4 bv[NT];
#pragma unroll
  for (int nt = 0; nt < NT; ++nt)
    bv[nt] = *(const floatx4*)(bias + n0 + nt * 16 + quad * 4);

  floatx4 acc[MT][NT];
#pragma unroll
  for (int mt = 0; mt < MT; ++mt)
#pragma unroll
    for (int nt = 0; nt < NT; ++nt)
      acc[mt][nt] = (floatx4){0.f, 0.f, 0.f, 0.f};

  half8 bbuf[4][NT];
#pragma unroll
  for (int s = 0; s < 3; ++s)
#pragma unroll
    for (int nt = 0; nt < NT; ++nt)
      bbuf[s][nt] = *(const half8*)(bp + (size_t)s * (TNT * 512) + nt * 512);

#pragma unroll
  for (int kb = 0; kb < KB; ++kb) {
    const int cur = kb & 3;
    half8 av[MT];
#pragma unroll
    for (int mt = 0; mt < MT; ++mt)
      av[mt] = *(const half8*)(srcA + (m0 + mt * 16 + lr) * STRIDE + kb * 32 + quad * 8);
    __builtin_amdgcn_s_setprio(1);
#pragma unroll
    for (int nt = 0; nt < NT; ++nt)
#pragma unroll
      for (int mt = 0; mt < MT; ++mt)
        acc[mt][nt] = __builtin_amdgcn_mfma_f32_16x16x32_f16(bbuf[cur][nt], av[mt], acc[mt][nt], 0, 0, 0);
    __builtin_amdgcn_s_setprio(0);
    if (kb + 3 < KB) {
      const int nxt = (kb + 3) & 3;
#pragma unroll
      for (int nt = 0; nt < NT; ++nt)
        bbuf[nxt][nt] = *(const half8*)(bp + (size_t)(kb + 3) * (TNT * 512) + nt * 512);
    }
  }

  // epilogue straight after own MFMAs: dst buffer != src buffer (no WAR)
#pragma unroll
  for (int nt = 0; nt < NT; ++nt) {
    const int c0 = n0 + nt * 16 + quad * 4;
#pragma unroll
    for (int mt = 0; mt < MT; ++mt) {
      const int r = m0 + mt * 16 + lr;
      floatx4 v = acc[mt][nt] + bv[nt];
      if (OUT_MODE <= 2) {
        half4 h;
#pragma unroll
        for (int reg = 0; reg < 4; ++reg) h[reg] = (_Float16)fmaxf(v[reg], 0.f);
        int a;
        if (OUT_MODE == 0)      a = r * 264 + c0;                         // encode
        else if (OUT_MODE == 1) a = (r >> 1) * 520 + (r & 1) * 256 + c0;  // concat
        else                    a = r * 520 + c0;                         // head
        *(half4*)(dstA + a) = h;                                          // 8B write
      } else {
        if (r < 50) {
          floatx4 o;
#pragma unroll
          for (int reg = 0; reg < 4; ++reg) o[reg] = 1.0f / (1.0f + expf(-v[reg]));
          *(floatx4*)(outg + (size_t)(pair0 + r) * 64 + c0) = o;          // 16B store
        }
      }
    }
  }
}

// -------- megakernel: 50 pairs (100 side rows, pad 112) per 1024-thr block --
__global__ __launch_bounds__(1024) void v18_mega(
    const float* __restrict__ x1, const float* __restrict__ x2,
    const float* __restrict__ W1, const float* __restrict__ b1,
    const _Float16* __restrict__ Bf,
    const float* __restrict__ b2, const float* __restrict__ b3,
    const float* __restrict__ bl1, const float* __restrict__ bl2,
    const float* __restrict__ bl3, const float* __restrict__ bl4,
    float* __restrict__ outg) {
  // ping-pong buffers: encode [112][264]=29568 halves; head [64][520]=33280
  __shared__ _Float16 sB0[33280];
  __shared__ _Float16 sB1[33280];
  __shared__ float sM[112][3];

  int tid = threadIdx.x;
  int wave = tid >> 6, lane = tid & 63;
  int pair0 = blockIdx.x * 50;

  // Phase -1: guarantee sB0 is fully finite after L1. L1 writes encode halves
  // [0,29568); H1 later reads head rows 56..63 = halves [29120,33280). Zero
  // the never-written tail [29568,33280) plus overlap (cheap, one pass).
  for (int i = tid; i < 2080; i += 1024) ((float*)sB0)[14560 + i] = 0.f;

  // Phase 0: per-side-row mean of the 4 node coords (100 real rows, 12 pad)
  if (tid < 112) {
    int r = tid;
    float a0 = 0.f, a1 = 0.f, a2 = 0.f;
    if (r < 100) {
      int g = pair0 + (r >> 1);                    // always < 12500
      const float* q = ((r & 1) ? x2 : x1) + (size_t)g * 12;
      a0 = 0.25f * (q[0] + q[3] + q[6] + q[9]);
      a1 = 0.25f * (q[1] + q[4] + q[7] + q[10]);
      a2 = 0.25f * (q[2] + q[5] + q[8] + q[11]);
    }
    sM[r][0] = a0; sM[r][1] = a1; sM[r][2] = a2;
  }
  __syncthreads();

  // Phase 1: L1 (3 -> 256), fp32 VALU, packed half4 writes into sB0.
  {
    int c4 = (tid & 63) * 4;          // 0..252
    int rb = tid >> 6;                // 0..15
    floatx4 w0 = *(const floatx4*)(W1 + c4);
    floatx4 w1 = *(const floatx4*)(W1 + 256 + c4);
    floatx4 w2 = *(const floatx4*)(W1 + 512 + c4);
    floatx4 bb = *(const floatx4*)(b1 + c4);
    for (int r = rb; r < 112; r += 16) {
      float s0 = sM[r][0], s1 = sM[r][1], s2 = sM[r][2];
      half4 h;
#pragma unroll
      for (int j = 0; j < 4; ++j) {
        float v = fmaxf(s0 * w0[j] + s1 * w1[j] + s2 * w2[j] + bb[j], 0.f);
        h[j] = (_Float16)v;
      }
      *(half4*)(sB0 + r * 264 + c4) = h;
    }
  }
  __syncthreads();

  // L2: [112x256]@[256x256] relu, sB0->sB1   (Wn=8 x Wm=2: rows 0..63 / 64..111)
  if (wave < 8) layer<4, 2, 16,  8, true,  0>(Bf + 0,      b2,  sB0, sB1, nullptr, pair0, wave,     0,  lane);
  else          layer<3, 2, 16,  8, true,  0>(Bf + 0,      b2,  sB0, sB1, nullptr, pair0, wave - 8, 64, lane);
  __syncthreads();
  // L3: [112x256]@[256x256] relu, sB1->sB0 (concat head layout)
  if (wave < 8) layer<4, 2, 16,  8, true,  1>(Bf + 65536,  b3,  sB1, sB0, nullptr, pair0, wave,     0,  lane);
  else          layer<3, 2, 16,  8, true,  1>(Bf + 65536,  b3,  sB1, sB0, nullptr, pair0, wave - 8, 64, lane);
  __syncthreads();
  // H1: [64x512]@[512x512] relu, sB0->sB1    (Wn=16 x NT=2; B-heavy, no m-split)
  layer<4, 2, 32, 16, false, 2>(Bf + 131072, bl1, sB0, sB1, nullptr, pair0, wave, 0, lane);
  __syncthreads();
  // H2: [64x512]@[512x256] relu, sB1->sB0    (Wn=8 x Wm=2: rows 0..31 / 32..63)
  if (wave < 8) layer<2, 2, 16, 16, false, 2>(Bf + 393216, bl2, sB1, sB0, nullptr, pair0, wave,     0,  lane);
  else          layer<2, 2, 16, 16, false, 2>(Bf + 393216, bl2, sB1, sB0, nullptr, pair0, wave - 8, 32, lane);
  __syncthreads();
  // H3: [64x256]@[256x128] relu, sB0->sB1    (Wn=8 x Wm=2)
  layer<2, 1,  8,  8, false, 2>(Bf + 524288, bl3, sB0, sB1, nullptr, pair0,
                                wave & 7, (wave >> 3) * 32, lane);
  __syncthreads();
  // H4: [64x128]@[128x64] sigmoid -> global  (Wn=4 x Wm=4)
  layer<1, 1,  4,  4, false, 3>(Bf + 557056, bl4, sB1, nullptr, outg, pair0,
                                wave & 3, (wave >> 2) * 16, lane);
}

extern "C" void kernel_launch(void* const* d_in, const int* in_sizes, int n_in,
                              void* d_out, int out_size, void* d_ws, size_t ws_size,
                              hipStream_t stream) {
  const float* x1  = (const float*)d_in[0];
  const float* x2  = (const float*)d_in[3];
  const float* W1  = (const float*)d_in[6];
  const float* b1  = (const float*)d_in[7];
  const float* W2  = (const float*)d_in[8];
  const float* b2  = (const float*)d_in[9];
  const float* W3  = (const float*)d_in[10];
  const float* b3  = (const float*)d_in[11];
  const float* Wl1 = (const float*)d_in[12];
  const float* bl1 = (const float*)d_in[13];
  const float* Wl2 = (const float*)d_in[14];
  const float* bl2 = (const float*)d_in[15];
  const float* Wl3 = (const float*)d_in[16];
  const float* bl3 = (const float*)d_in[17];
  const float* Wl4 = (const float*)d_in[18];
  const float* bl4 = (const float*)d_in[19];

  _Float16* Bf = (_Float16*)d_ws;   // 565248 halves = 1.13 MB

  PrepArgsV18 pa;
  pa.in[0] = W2;  pa.in[1] = W3;  pa.in[2] = Wl1;
  pa.in[3] = Wl2; pa.in[4] = Wl3; pa.in[5] = Wl4;

  v18_prep<<<dim3(138), dim3(256), 0, stream>>>(pa, Bf);
  v18_mega<<<dim3(250), dim3(1024), 0, stream>>>(x1, x2, W1, b1, Bf,
                                                 b2, b3, bl1, bl2, bl3, bl4,
                                                 (float*)d_out);
}

// Round 6
// 116.454 us; speedup vs baseline: 1.0082x; 1.0018x over previous
//
#include <hip/hip_runtime.h>

// GraphPairClassifier v19: v16 core + raw-barrier cross-layer B prefetch.
//   R17 lesson: __syncthreads() drains vmcnt(0) -> pre-barrier B preloads
//   were serialized AT the barrier. R19 fix (per the verified 8-phase
//   template, T3/T4): inter-layer sync = {s_waitcnt lgkmcnt(0); raw
//   s_barrier; sched_barrier(0)}. lgkmcnt(0) covers own ds_writes (make
//   visible) AND own ds_reads (ping-pong WAR safety); raw s_barrier does
//   NOT drain vmcnt -> next layer's 3xNT B-warmup loads (issued after the
//   epilogue, before the barrier) fly across and their L2 latency hides
//   under the barrier wait + next layer's A ds_reads. setprio removed
//   (m190: null-to-negative in barrier-lockstep). Bias-hoist kept.
//   Geometry: 250 blocks x 50 pairs x 1024 thr (16 waves, 4/SIMD),
//   ping-pong LDS, m-split L2/L3/H2/H3, transposed-MFMA D^T epilogue,
//   distance-3 B prefetch, wide float2 prep.
// Dtypes: device inputs FP32 (bf16-quantized values => fp16 weights exact);
//   output FP32. absmax 3.9e-3 stable R6-R18.

typedef _Float16 half8  __attribute__((ext_vector_type(8)));
typedef _Float16 half4  __attribute__((ext_vector_type(4)));
typedef _Float16 half16 __attribute__((ext_vector_type(16)));
typedef float floatx4 __attribute__((ext_vector_type(4)));

// inter-layer barrier: own DS ops drained, vmem (B preloads) stays in flight
#define LAYER_BARRIER() do {                                   \
    asm volatile("s_waitcnt lgkmcnt(0)" ::: "memory");         \
    __builtin_amdgcn_s_barrier();                              \
    __builtin_amdgcn_sched_barrier(0);                         \
  } while (0)

// -------- weight prep: fp32 [K,N] row-major -> fp16 16x16x32-fragment order -
// Storage slot f (half8): lane=f&63, rem=f>>6, nt=rem%(N/16), kb=rem/(N/16);
//   n = nt*16+(lane&15), k = kb*32+(lane>>4)*8+j.
// Unit u = slots {2u, 2u+1} (lanes l0=2t, l0+1 of rem=u>>5, t=u&31):
//   8 x float2 strided reads (n0 even), one 32B contiguous write.
struct PrepArgsV19 { const float* in[6]; };

__global__ __launch_bounds__(256) void v19_prep(PrepArgsV19 p, _Float16* Bf) {
  const int units[6] = {4096, 4096, 16384, 8192, 2048, 512};  // sz/16
  const int lgN[6]   = {8, 8, 9, 8, 7, 6};
  const int off[6]   = {0, 65536, 131072, 393216, 524288, 557056};
  int u = blockIdx.x * 256 + threadIdx.x;           // 138 blocks x 256 = 35328
  for (int i = 0; i < 6; ++i) {
    if (u < units[i]) {
      int N = 1 << lgN[i];
      int t = u & 31, rem = u >> 5;
      int nt = rem & ((N >> 4) - 1);
      int kb = rem >> (lgN[i] - 4);
      int lr0 = (2 * t) & 15;                       // even, lanes l0 & l0+1 same quad
      int quad = t >> 3;
      int n0 = nt * 16 + lr0;
      int k0 = kb * 32 + quad * 8;
      const float* src = p.in[i] + (size_t)k0 * N + n0;
      half16 w;
#pragma unroll
      for (int j = 0; j < 8; ++j) {
        float2 f2 = *(const float2*)(src + (size_t)j * N);   // 8B aligned (n0 even)
        w[j]     = (_Float16)f2.x;                  // slot 2u   (lane l0,   n0)
        w[8 + j] = (_Float16)f2.y;                  // slot 2u+1 (lane l0+1, n0+1)
      }
      *(half16*)(Bf + off[i] + (size_t)u * 16) = w; // 32B store, exact (bf16-valued)
      return;
    }
    u -= units[i];
  }
}

// -------- cross-layer B warmup: load k-steps 0..2 into caller-owned bbuf ----
template<int NT, int TNT>
__device__ __forceinline__ void preload(half8 (&bbuf)[4][2], const _Float16* bp) {
#pragma unroll
  for (int s = 0; s < 3; ++s)
#pragma unroll
    for (int nt = 0; nt < NT; ++nt)
      bbuf[s][nt] = *(const half8*)(bp + (size_t)s * (TNT * 512) + nt * 512);
}

// -------- generic ping-pong layer, distance-3 B prefetch, D^T epilogue -----
// MT m-tiles (16 rows from m0), NT n-tiles at n-slot nw, TNT = N/16 total
// n-tiles, KB k-steps of 32. ENC_IN: srcA stride 264 halves; else 520.
// OUT_MODE 0: relu->encode(dst); 1: relu->head concat(dst); 2: relu->head(dst);
//          3: sigmoid->global fp32 (rows r<50 only).
// bbuf slots 0..2 arrive PRELOADED (issued pre-barrier by the caller; raw
// barrier keeps them in flight). Bias loaded at entry (hides under K-loop).
// mfma(a_op=W frag, b_op=Act frag) => D^T: r = m0+mt*16+(lane&15),
//   c = n0+nt*16+quad*4+reg (4 consecutive cols per lane -> packed writes).
// NO trailing barrier here — caller syncs (calls may be wave-divergent).
template<int MT, int NT, int TNT, int KB, bool ENC_IN, int OUT_MODE>
__device__ __forceinline__ void layer(
    const _Float16* __restrict__ Bf, const float* __restrict__ bias,
    const _Float16* __restrict__ srcA, _Float16* dstA, float* __restrict__ outg,
    half8 (&bbuf)[4][2], int pair0, int nw, int m0, int lane) {
  const int quad = lane >> 4, lr = lane & 15;
  const int n0 = nw * (NT * 16);
  const int STRIDE = ENC_IN ? 264 : 520;
  const _Float16* bp = Bf + ((size_t)(nw * NT) * 64 + lane) * 8;

  // bias hoist: issue global loads now, consume after the K-loop
  floatx4 bv[NT];
#pragma unroll
  for (int nt = 0; nt < NT; ++nt)
    bv[nt] = *(const floatx4*)(bias + n0 + nt * 16 + quad * 4);

  floatx4 acc[MT][NT];
#pragma unroll
  for (int mt = 0; mt < MT; ++mt)
#pragma unroll
    for (int nt = 0; nt < NT; ++nt)
      acc[mt][nt] = (floatx4){0.f, 0.f, 0.f, 0.f};

#pragma unroll
  for (int kb = 0; kb < KB; ++kb) {
    const int cur = kb & 3;
    half8 av[MT];
#pragma unroll
    for (int mt = 0; mt < MT; ++mt)
      av[mt] = *(const half8*)(srcA + (m0 + mt * 16 + lr) * STRIDE + kb * 32 + quad * 8);
#pragma unroll
    for (int nt = 0; nt < NT; ++nt)
#pragma unroll
      for (int mt = 0; mt < MT; ++mt)
        acc[mt][nt] = __builtin_amdgcn_mfma_f32_16x16x32_f16(bbuf[cur][nt], av[mt], acc[mt][nt], 0, 0, 0);
    if (kb + 3 < KB) {
      const int nxt = (kb + 3) & 3;
#pragma unroll
      for (int nt = 0; nt < NT; ++nt)
        bbuf[nxt][nt] = *(const half8*)(bp + (size_t)(kb + 3) * (TNT * 512) + nt * 512);
    }
  }

  // epilogue straight after own MFMAs: dst buffer != src buffer (no WAR)
#pragma unroll
  for (int nt = 0; nt < NT; ++nt) {
    const int c0 = n0 + nt * 16 + quad * 4;
#pragma unroll
    for (int mt = 0; mt < MT; ++mt) {
      const int r = m0 + mt * 16 + lr;
      floatx4 v = acc[mt][nt] + bv[nt];
      if (OUT_MODE <= 2) {
        half4 h;
#pragma unroll
        for (int reg = 0; reg < 4; ++reg) h[reg] = (_Float16)fmaxf(v[reg], 0.f);
        int a;
        if (OUT_MODE == 0)      a = r * 264 + c0;                         // encode
        else if (OUT_MODE == 1) a = (r >> 1) * 520 + (r & 1) * 256 + c0;  // concat
        else                    a = r * 520 + c0;                         // head
        *(half4*)(dstA + a) = h;                                          // 8B write
      } else {
        if (r < 50) {
          floatx4 o;
#pragma unroll
          for (int reg = 0; reg < 4; ++reg) o[reg] = 1.0f / (1.0f + expf(-v[reg]));
          *(floatx4*)(outg + (size_t)(pair0 + r) * 64 + c0) = o;          // 16B store
        }
      }
    }
  }
}

// -------- megakernel: 50 pairs (100 side rows, pad 112) per 1024-thr block --
__global__ __launch_bounds__(1024) void v19_mega(
    const float* __restrict__ x1, const float* __restrict__ x2,
    const float* __restrict__ W1, const float* __restrict__ b1,
    const _Float16* __restrict__ Bf,
    const float* __restrict__ b2, const float* __restrict__ b3,
    const float* __restrict__ bl1, const float* __restrict__ bl2,
    const float* __restrict__ bl3, const float* __restrict__ bl4,
    float* __restrict__ outg) {
  // ping-pong buffers: encode [112][264]=29568 halves; head [64][520]=33280
  __shared__ _Float16 sB0[33280];
  __shared__ _Float16 sB1[33280];
  __shared__ float sM[112][3];

  int tid = threadIdx.x;
  int wave = tid >> 6, lane = tid & 63;
  int pair0 = blockIdx.x * 50;
  int nwA = (wave < 8) ? wave : wave - 8;   // n-slot for the m-split layers

  // Phase -1: guarantee sB0 is fully finite after L1. L1 writes encode halves
  // [0,29568); H1 later reads head rows 56..63 = halves [29120,33280). Zero
  // the never-written tail [29568,33280) plus overlap (cheap, one pass).
  for (int i = tid; i < 2080; i += 1024) ((float*)sB0)[14560 + i] = 0.f;

  // Phase 0: per-side-row mean of the 4 node coords (100 real rows, 12 pad)
  if (tid < 112) {
    int r = tid;
    float a0 = 0.f, a1 = 0.f, a2 = 0.f;
    if (r < 100) {
      int g = pair0 + (r >> 1);                    // always < 12500
      const float* q = ((r & 1) ? x2 : x1) + (size_t)g * 12;
      a0 = 0.25f * (q[0] + q[3] + q[6] + q[9]);
      a1 = 0.25f * (q[1] + q[4] + q[7] + q[10]);
      a2 = 0.25f * (q[2] + q[5] + q[8] + q[11]);
    }
    sM[r][0] = a0; sM[r][1] = a1; sM[r][2] = a2;
  }
  __syncthreads();

  // Phase 1: L1 (3 -> 256), fp32 VALU, packed half4 writes into sB0.
  {
    int c4 = (tid & 63) * 4;          // 0..252
    int rb = tid >> 6;                // 0..15
    floatx4 w0 = *(const floatx4*)(W1 + c4);
    floatx4 w1 = *(const floatx4*)(W1 + 256 + c4);
    floatx4 w2 = *(const floatx4*)(W1 + 512 + c4);
    floatx4 bb = *(const floatx4*)(b1 + c4);
    for (int r = rb; r < 112; r += 16) {
      float s0 = sM[r][0], s1 = sM[r][1], s2 = sM[r][2];
      half4 h;
#pragma unroll
      for (int j = 0; j < 4; ++j) {
        float v = fmaxf(s0 * w0[j] + s1 * w1[j] + s2 * w2[j] + bb[j], 0.f);
        h[j] = (_Float16)v;
      }
      *(half4*)(sB0 + r * 264 + c4) = h;
    }
  }
  // L2's B warmup: issue before the raw barrier; stays in flight across it
  half8 bbuf[4][2];
  preload<2, 16>(bbuf, Bf + ((size_t)(nwA * 2) * 64 + lane) * 8);
  LAYER_BARRIER();

  // L2: [112x256]@[256x256] relu, sB0->sB1   (Wn=8 x Wm=2: rows 0..63 / 64..111)
  if (wave < 8) layer<4, 2, 16,  8, true,  0>(Bf + 0,      b2,  sB0, sB1, nullptr, bbuf, pair0, nwA, 0,  lane);
  else          layer<3, 2, 16,  8, true,  0>(Bf + 0,      b2,  sB0, sB1, nullptr, bbuf, pair0, nwA, 64, lane);
  preload<2, 16>(bbuf, Bf + 65536 + ((size_t)(nwA * 2) * 64 + lane) * 8);
  LAYER_BARRIER();
  // L3: [112x256]@[256x256] relu, sB1->sB0 (concat head layout)
  if (wave < 8) layer<4, 2, 16,  8, true,  1>(Bf + 65536,  b3,  sB1, sB0, nullptr, bbuf, pair0, nwA, 0,  lane);
  else          layer<3, 2, 16,  8, true,  1>(Bf + 65536,  b3,  sB1, sB0, nullptr, bbuf, pair0, nwA, 64, lane);
  preload<2, 32>(bbuf, Bf + 131072 + ((size_t)(wave * 2) * 64 + lane) * 8);
  LAYER_BARRIER();
  // H1: [64x512]@[512x512] relu, sB0->sB1    (Wn=16 x NT=2; B-heavy, no m-split)
  layer<4, 2, 32, 16, false, 2>(Bf + 131072, bl1, sB0, sB1, nullptr, bbuf, pair0, wave, 0, lane);
  preload<2, 16>(bbuf, Bf + 393216 + ((size_t)(nwA * 2) * 64 + lane) * 8);
  LAYER_BARRIER();
  // H2: [64x512]@[512x256] relu, sB1->sB0    (Wn=8 x Wm=2: rows 0..31 / 32..63)
  if (wave < 8) layer<2, 2, 16, 16, false, 2>(Bf + 393216, bl2, sB1, sB0, nullptr, bbuf, pair0, nwA, 0,  lane);
  else          layer<2, 2, 16, 16, false, 2>(Bf + 393216, bl2, sB1, sB0, nullptr, bbuf, pair0, nwA, 32, lane);
  preload<1, 8>(bbuf, Bf + 524288 + ((size_t)(wave & 7) * 64 + lane) * 8);
  LAYER_BARRIER();
  // H3: [64x256]@[256x128] relu, sB0->sB1    (Wn=8 x Wm=2)
  layer<2, 1,  8,  8, false, 2>(Bf + 524288, bl3, sB0, sB1, nullptr, bbuf, pair0,
                                wave & 7, (wave >> 3) * 32, lane);
  preload<1, 4>(bbuf, Bf + 557056 + ((size_t)(wave & 3) * 64 + lane) * 8);
  LAYER_BARRIER();
  // H4: [64x128]@[128x64] sigmoid -> global  (Wn=4 x Wm=4)
  layer<1, 1,  4,  4, false, 3>(Bf + 557056, bl4, sB1, nullptr, outg, bbuf, pair0,
                                wave & 3, (wave >> 2) * 16, lane);
}

extern "C" void kernel_launch(void* const* d_in, const int* in_sizes, int n_in,
                              void* d_out, int out_size, void* d_ws, size_t ws_size,
                              hipStream_t stream) {
  const float* x1  = (const float*)d_in[0];
  const float* x2  = (const float*)d_in[3];
  const float* W1  = (const float*)d_in[6];
  const float* b1  = (const float*)d_in[7];
  const float* W2  = (const float*)d_in[8];
  const float* b2  = (const float*)d_in[9];
  const float* W3  = (const float*)d_in[10];
  const float* b3  = (const float*)d_in[11];
  const float* Wl1 = (const float*)d_in[12];
  const float* bl1 = (const float*)d_in[13];
  const float* Wl2 = (const float*)d_in[14];
  const float* bl2 = (const float*)d_in[15];
  const float* Wl3 = (const float*)d_in[16];
  const float* bl3 = (const float*)d_in[17];
  const float* Wl4 = (const float*)d_in[18];
  const float* bl4 = (const float*)d_in[19];

  _Float16* Bf = (_Float16*)d_ws;   // 565248 halves = 1.13 MB

  PrepArgsV19 pa;
  pa.in[0] = W2;  pa.in[1] = W3;  pa.in[2] = Wl1;
  pa.in[3] = Wl2; pa.in[4] = Wl3; pa.in[5] = Wl4;

  v19_prep<<<dim3(138), dim3(256), 0, stream>>>(pa, Bf);
  v19_mega<<<dim3(250), dim3(1024), 0, stream>>>(x1, x2, W1, b1, Bf,
                                                 b2, b3, bl1, bl2, bl3, bl4,
                                                 (float*)d_out);
}